// Round 1
// baseline (23521.320 us; speedup 1.0000x reference)
//
#include <hip/hip_runtime.h>
#include <math.h>

// LstmCellRudder: B=256, T=512, D=160 (obs 128 + act 32), H=512, gates 4H=2048.
// Round 1: fp32, one kernel per timestep (512 launches in the graph),
// h ping-pong in workspace, W tiles staged via LDS, thread owns (2 batches x
// 4 gates of one hidden j) so the c/h update is thread-local.

namespace {
constexpr int kB = 256, kT = 512, kNpos = 128, kNact = 32, kD = 160, kH = 512;

__global__ void lstm_init(const float* __restrict__ h0, const float* __restrict__ c0,
                          const float* __restrict__ b_out,
                          float* __restrict__ h_a, float* __restrict__ c_st,
                          float* __restrict__ out) {
    int i = blockIdx.x * blockDim.x + threadIdx.x;  // 0..131071 (B*H == B*T)
    h_a[i]  = h0[i];
    c_st[i] = c0[i];
    out[i]  = b_out[0];
}

__device__ __forceinline__ float sigmoidf_(float x) {
    return 1.0f / (1.0f + __expf(-x));
}

__global__ __launch_bounds__(256)
void lstm_step(int t,
               const float* __restrict__ obs, const float* __restrict__ act,
               const float* __restrict__ Wih, const float* __restrict__ Whh,
               const float* __restrict__ bih, const float* __restrict__ bhh,
               const float* __restrict__ Wout,
               const float* __restrict__ h_in, float* __restrict__ h_out,
               float* __restrict__ c_st, float* __restrict__ out) {
    // Wt row stride 36 floats: 144 B (16B aligned for b128), banks spread evenly.
    __shared__ float Wt[128][36];

    const int tid = threadIdx.x;
    const int tx  = tid & 31;   // j within j-tile (32)
    const int ty  = tid >> 5;   // batch-pair index (8 -> 16 batches)
    const int bt  = blockIdx.x; // 16 batch tiles
    const int jt  = blockIdx.y; // 16 j tiles
    const int j   = jt * 32 + tx;
    const int b0  = bt * 16 + ty * 2;

    float acc[2][4];
#pragma unroll
    for (int g = 0; g < 4; ++g) {
        float bs = bih[g * kH + j] + bhh[g * kH + j];
        acc[0][g] = bs;
        acc[1][g] = bs;
    }

    // staging assignment: 2 threads per W row (32 k each -> 16 floats/thread)
    const int r    = tid >> 1;   // 0..127 = gsel*32 + jj
    const int gsel = r >> 5;
    const int jj   = r & 31;
    const int wrow = gsel * kH + jt * 32 + jj;
    const int koff = (tid & 1) * 16;

    const long rowb0 = (long)b0 * kT + t;
    const float* xo0 = obs + rowb0 * kNpos;
    const float* xo1 = obs + (rowb0 + kT) * kNpos;
    const float* xa0 = act + rowb0 * kNact;
    const float* xa1 = act + (rowb0 + kT) * kNact;

    // ---------- phase X: k over D=160, 5 tiles of 32 ----------
    for (int ktile = 0; ktile < 5; ++ktile) {
        const int k0 = ktile * 32;
        __syncthreads();
        {
            const float* src = Wih + (long)wrow * kD + k0 + koff;
            float4 v0 = *(const float4*)(src + 0);
            float4 v1 = *(const float4*)(src + 4);
            float4 v2 = *(const float4*)(src + 8);
            float4 v3 = *(const float4*)(src + 12);
            float* dst = &Wt[r][koff];
            *(float4*)(dst + 0)  = v0;
            *(float4*)(dst + 4)  = v1;
            *(float4*)(dst + 8)  = v2;
            *(float4*)(dst + 12) = v3;
        }
        __syncthreads();
        const bool isObs = (k0 < kNpos);
        const float* x0 = isObs ? (xo0 + k0) : (xa0 + (k0 - kNpos));
        const float* x1 = isObs ? (xo1 + k0) : (xa1 + (k0 - kNpos));
#pragma unroll
        for (int kk = 0; kk < 8; ++kk) {
            float4 xv0 = *(const float4*)(x0 + kk * 4);
            float4 xv1 = *(const float4*)(x1 + kk * 4);
#pragma unroll
            for (int g = 0; g < 4; ++g) {
                float4 w = *(const float4*)&Wt[g * 32 + tx][kk * 4];
                acc[0][g] = fmaf(xv0.x, w.x, acc[0][g]);
                acc[0][g] = fmaf(xv0.y, w.y, acc[0][g]);
                acc[0][g] = fmaf(xv0.z, w.z, acc[0][g]);
                acc[0][g] = fmaf(xv0.w, w.w, acc[0][g]);
                acc[1][g] = fmaf(xv1.x, w.x, acc[1][g]);
                acc[1][g] = fmaf(xv1.y, w.y, acc[1][g]);
                acc[1][g] = fmaf(xv1.z, w.z, acc[1][g]);
                acc[1][g] = fmaf(xv1.w, w.w, acc[1][g]);
            }
        }
    }

    // ---------- phase H: k over H=512, 16 tiles of 32 ----------
    const float* h0p = h_in + (long)b0 * kH;
    const float* h1p = h_in + (long)(b0 + 1) * kH;
    for (int ktile = 0; ktile < 16; ++ktile) {
        const int k0 = ktile * 32;
        __syncthreads();
        {
            const float* src = Whh + (long)wrow * kH + k0 + koff;
            float4 v0 = *(const float4*)(src + 0);
            float4 v1 = *(const float4*)(src + 4);
            float4 v2 = *(const float4*)(src + 8);
            float4 v3 = *(const float4*)(src + 12);
            float* dst = &Wt[r][koff];
            *(float4*)(dst + 0)  = v0;
            *(float4*)(dst + 4)  = v1;
            *(float4*)(dst + 8)  = v2;
            *(float4*)(dst + 12) = v3;
        }
        __syncthreads();
#pragma unroll
        for (int kk = 0; kk < 8; ++kk) {
            float4 xv0 = *(const float4*)(h0p + k0 + kk * 4);
            float4 xv1 = *(const float4*)(h1p + k0 + kk * 4);
#pragma unroll
            for (int g = 0; g < 4; ++g) {
                float4 w = *(const float4*)&Wt[g * 32 + tx][kk * 4];
                acc[0][g] = fmaf(xv0.x, w.x, acc[0][g]);
                acc[0][g] = fmaf(xv0.y, w.y, acc[0][g]);
                acc[0][g] = fmaf(xv0.z, w.z, acc[0][g]);
                acc[0][g] = fmaf(xv0.w, w.w, acc[0][g]);
                acc[1][g] = fmaf(xv1.x, w.x, acc[1][g]);
                acc[1][g] = fmaf(xv1.y, w.y, acc[1][g]);
                acc[1][g] = fmaf(xv1.z, w.z, acc[1][g]);
                acc[1][g] = fmaf(xv1.w, w.w, acc[1][g]);
            }
        }
    }

    // ---------- epilogue: gate nonlinearities, c/h update, y reduction ----------
#pragma unroll
    for (int bp = 0; bp < 2; ++bp) {
        const int b = b0 + bp;
        float ig = sigmoidf_(acc[bp][0]);
        float fg = sigmoidf_(acc[bp][1]);
        float gg = tanhf(acc[bp][2]);
        float og = sigmoidf_(acc[bp][3]);
        float cv = c_st[b * kH + j];
        float cn = fmaf(fg, cv, ig * gg);
        c_st[b * kH + j] = cn;
        float hn = og * tanhf(cn);
        h_out[b * kH + j] = hn;
        float p = hn * Wout[j];
        // reduce over the 32 j-lanes (xor<32 stays within the half-wave)
#pragma unroll
        for (int s = 16; s > 0; s >>= 1) p += __shfl_xor(p, s);
        if (tx == 0) atomicAdd(&out[b * kT + t], p);
    }
}

}  // namespace

extern "C" void kernel_launch(void* const* d_in, const int* in_sizes, int n_in,
                              void* d_out, int out_size, void* d_ws, size_t ws_size,
                              hipStream_t stream) {
    const float* obs  = (const float*)d_in[0];
    const float* act  = (const float*)d_in[1];
    const float* Wih  = (const float*)d_in[2];
    const float* Whh  = (const float*)d_in[3];
    const float* bih  = (const float*)d_in[4];
    const float* bhh  = (const float*)d_in[5];
    const float* Wout = (const float*)d_in[6];
    const float* bout = (const float*)d_in[7];
    const float* h0   = (const float*)d_in[8];
    const float* c0   = (const float*)d_in[9];
    float* out = (float*)d_out;

    float* ws   = (float*)d_ws;
    float* h_a  = ws;                 // [B*H]
    float* h_b  = ws + kB * kH;       // [B*H]
    float* c_st = ws + 2 * kB * kH;   // [B*H]

    lstm_init<<<(kB * kH) / 256, 256, 0, stream>>>(h0, c0, bout, h_a, c_st, out);

    const float* hin = h_a;
    float* hout = h_b;
    for (int t = 0; t < kT; ++t) {
        lstm_step<<<dim3(16, 16), 256, 0, stream>>>(t, obs, act, Wih, Whh, bih, bhh,
                                                    Wout, hin, hout, c_st, out);
        float* tmp = (float*)hin;
        hin = hout;
        hout = tmp;
    }
}